// Round 1
// baseline (9126.044 us; speedup 1.0000x reference)
//
#include <hip/hip_runtime.h>
#include <hip/hip_bf16.h>
#include <cstdint>
#include <cstddef>

#define NN 100000
#define DD 128
#define NE 1600000

// ---------------------------------------------------------------------------
// Scatter-add aggregation: prop[dst[e]] += h[src[e]]  (segment_sum)
// Each thread handles one float4 chunk (4 floats) of one edge.
// ---------------------------------------------------------------------------
__global__ __launch_bounds__(256)
void scatter_kernel(const float* __restrict__ h, const int* __restrict__ ei,
                    float* __restrict__ prop, int n_edges) {
    const long long total = (long long)n_edges * 32;  // 32 float4 chunks per edge
    long long t0 = (long long)blockIdx.x * blockDim.x + threadIdx.x;
    long long stride = (long long)gridDim.x * blockDim.x;
    for (long long t = t0; t < total; t += stride) {
        int e = (int)(t >> 5);
        int c = (int)(t & 31);
        int s = ei[e];
        int d = ei[n_edges + e];
        float4 v = reinterpret_cast<const float4*>(h + (size_t)s * DD)[c];
        float* p = prop + (size_t)d * DD + (size_t)c * 4;
        atomicAdd(p + 0, v.x);
        atomicAdd(p + 1, v.y);
        atomicAdd(p + 2, v.z);
        atomicAdd(p + 3, v.w);
    }
}

// ---------------------------------------------------------------------------
// Fused GEMM layer:
//   DUAL=true : out = h @ W1^T + b1 + prop @ W2^T + b2, then (NORM_RELU) L2-
//               normalize rows + ReLU.
//   DUAL=false: out = h @ W1^T + b1  (post1)
// W rows staged in LDS padded to 132 floats (33 float4) -> conflict-free
// ds_read_b128 across lanes. 512 threads, 4 nodes per iteration
// (thread = group g (node) * 128 + output dim d).
// ---------------------------------------------------------------------------
template<bool DUAL, bool NORM_RELU>
__global__ __launch_bounds__(512)
void gemm_kernel(const float* __restrict__ h, const float* __restrict__ prop,
                 const float* __restrict__ W1, const float* __restrict__ b1,
                 const float* __restrict__ W2, const float* __restrict__ b2,
                 float* __restrict__ out, int n_nodes) {
    __shared__ float w1_s[DD * 132];
    __shared__ float w2_s[DUAL ? DD * 132 : 4];
    __shared__ float h_s[4][DD];
    __shared__ float p_s[DUAL ? 4 : 1][DD];
    __shared__ float red_s[8];

    const int tid = threadIdx.x;

    // Stage weights into LDS (132-float padded rows).
    {
        const float4* g1 = reinterpret_cast<const float4*>(W1);
        float4* s1 = reinterpret_cast<float4*>(w1_s);
        for (int j = tid; j < DD * 32; j += 512) {
            int r = j >> 5, c = j & 31;
            s1[r * 33 + c] = g1[j];
        }
        if (DUAL) {
            const float4* g2 = reinterpret_cast<const float4*>(W2);
            float4* s2 = reinterpret_cast<float4*>(w2_s);
            for (int j = tid; j < DD * 32; j += 512) {
                int r = j >> 5, c = j & 31;
                s2[r * 33 + c] = g2[j];
            }
        }
    }

    const int g = tid >> 7;    // node group within iteration (0..3)
    const int d = tid & 127;   // output dim
    float bias = b1[d] + (DUAL ? b2[d] : 0.0f);
    __syncthreads();

    const float4* w1_4 = reinterpret_cast<const float4*>(w1_s);
    const float4* w2_4 = DUAL ? reinterpret_cast<const float4*>(w2_s) : nullptr;

    for (int base = blockIdx.x * 4; base < n_nodes; base += gridDim.x * 4) {
        // Cooperative staging of 4 node rows of h (and prop).
        {
            int n_load = base + (tid >> 7);
            int k = tid & 127;
            if (n_load < n_nodes) {
                h_s[tid >> 7][k] = h[(size_t)n_load * DD + k];
                if (DUAL) p_s[tid >> 7][k] = prop[(size_t)n_load * DD + k];
            }
        }
        __syncthreads();

        const float4* hv4 = reinterpret_cast<const float4*>(h_s[g]);
        float acc1 = 0.0f, acc2 = 0.0f;
        #pragma unroll
        for (int c = 0; c < 32; ++c) {
            float4 hv = hv4[c];
            float4 wv = w1_4[d * 33 + c];
            acc1 += hv.x * wv.x + hv.y * wv.y + hv.z * wv.z + hv.w * wv.w;
            if (DUAL) {
                float4 pv = reinterpret_cast<const float4*>(p_s[g])[c];
                float4 w2v = w2_4[d * 33 + c];
                acc2 += pv.x * w2v.x + pv.y * w2v.y + pv.z * w2v.z + pv.w * w2v.w;
            }
        }
        float val = acc1 + acc2 + bias;

        int n = base + g;
        if (NORM_RELU) {
            float ss = val * val;
            #pragma unroll
            for (int o = 32; o > 0; o >>= 1) ss += __shfl_xor(ss, o);
            if ((tid & 63) == 0) red_s[tid >> 6] = ss;   // one partial per wave
            __syncthreads();
            float tot = red_s[g * 2] + red_s[g * 2 + 1];
            float norm = fmaxf(sqrtf(tot), 1e-12f);
            val = fmaxf(val / norm, 0.0f);
        }
        if (n < n_nodes) out[(size_t)n * DD + d] = val;
        __syncthreads();  // protect h_s / red_s before next iteration's staging
    }
}

// ---------------------------------------------------------------------------
// Post2 + log_softmax: out[n][l] = log_softmax(hin[n] @ W2^T + b2), l<40.
// One wave per node; W2 staged in LDS (padded rows).
// ---------------------------------------------------------------------------
__global__ __launch_bounds__(256)
void post2_kernel(const float* __restrict__ hin, const float* __restrict__ W2,
                  const float* __restrict__ b2, float* __restrict__ out,
                  int n_nodes) {
    __shared__ float w_s[40 * 132];
    __shared__ float row_s[4][DD];
    const int tid = threadIdx.x;

    {
        const float4* gw = reinterpret_cast<const float4*>(W2);
        float4* sw = reinterpret_cast<float4*>(w_s);
        for (int j = tid; j < 40 * 32; j += 256) {
            int r = j >> 5, c = j & 31;
            sw[r * 33 + c] = gw[j];
        }
    }
    __syncthreads();

    const int wave = tid >> 6;
    const int lane = tid & 63;
    const float4* w4 = reinterpret_cast<const float4*>(w_s);
    const int lr = (lane < 40) ? lane : 0;
    const float bias = (lane < 40) ? b2[lr] : 0.0f;

    for (int base = blockIdx.x * 4; base < n_nodes; base += gridDim.x * 4) {
        int n = base + wave;
        bool alive = (n < n_nodes);
        if (alive) {
            row_s[wave][lane] = hin[(size_t)n * DD + lane];
            row_s[wave][64 + lane] = hin[(size_t)n * DD + 64 + lane];
        }
        __syncthreads();

        float acc = bias;
        const float4* r4 = reinterpret_cast<const float4*>(row_s[wave]);
        #pragma unroll
        for (int c = 0; c < 32; ++c) {
            float4 rv = r4[c];
            float4 wv = w4[lr * 33 + c];
            acc += rv.x * wv.x + rv.y * wv.y + rv.z * wv.z + rv.w * wv.w;
        }

        float m = (alive && lane < 40) ? acc : -INFINITY;
        #pragma unroll
        for (int o = 32; o > 0; o >>= 1) m = fmaxf(m, __shfl_xor(m, o));
        float e = (alive && lane < 40) ? expf(acc - m) : 0.0f;
        #pragma unroll
        for (int o = 32; o > 0; o >>= 1) e += __shfl_xor(e, o);

        if (alive && lane < 40) out[(size_t)n * 40 + lane] = acc - m - logf(e);
        __syncthreads();
    }
}

// ---------------------------------------------------------------------------
extern "C" void kernel_launch(void* const* d_in, const int* in_sizes, int n_in,
                              void* d_out, int out_size, void* d_ws, size_t ws_size,
                              hipStream_t stream) {
    const float* x  = (const float*)d_in[0];
    const int*   ei = (const int*)d_in[1];
    const float* Wl = (const float*)d_in[2];
    const float* bl = (const float*)d_in[3];
    const float* Wr = (const float*)d_in[4];
    const float* br = (const float*)d_in[5];
    const float* W1 = (const float*)d_in[6];
    const float* b1 = (const float*)d_in[7];
    const float* W2 = (const float*)d_in[8];
    const float* b2 = (const float*)d_in[9];
    float* outp = (float*)d_out;

    // Workspace layout: prop | hA | hB  (each NN*DD floats = 51.2 MB)
    float* prop = (float*)d_ws;
    float* hA = prop + (size_t)NN * DD;
    float* hB = hA + (size_t)NN * DD;

    const float* hcur = x;
    float* hnext = hA;
    for (int i = 0; i < 3; ++i) {
        hipMemsetAsync(prop, 0, (size_t)NN * DD * sizeof(float), stream);
        scatter_kernel<<<8192, 256, 0, stream>>>(hcur, ei, prop, NE);
        gemm_kernel<true, true><<<256, 512, 0, stream>>>(
            hcur, prop,
            Wl + (size_t)i * DD * DD, bl + (size_t)i * DD,
            Wr + (size_t)i * DD * DD, br + (size_t)i * DD,
            hnext, NN);
        hcur = hnext;
        hnext = (hnext == hA) ? hB : hA;
    }
    // post1: hcur @ W_post1^T + b_post1 -> hnext
    gemm_kernel<false, false><<<512, 512, 0, stream>>>(
        hcur, nullptr, W1, b1, nullptr, nullptr, hnext, NN);
    // post2 + log_softmax -> d_out
    post2_kernel<<<1024, 256, 0, stream>>>(hnext, W2, b2, outp, NN);
}

// Round 2
// 1700.348 us; speedup vs baseline: 5.3672x; 5.3672x over previous
//
#include <hip/hip_runtime.h>
#include <hip/hip_bf16.h>
#include <cstdint>
#include <cstddef>

#define NN 100000
#define DD 128
#define NE 1600000

// ---------------------------------------------------------------------------
// CSR build: degree histogram over dst
// ---------------------------------------------------------------------------
__global__ __launch_bounds__(256)
void deg_kernel(const int* __restrict__ ei, int* __restrict__ deg, int n_edges) {
    int t0 = blockIdx.x * blockDim.x + threadIdx.x;
    int stride = gridDim.x * blockDim.x;
    for (int e = t0; e < n_edges; e += stride) {
        atomicAdd(&deg[ei[n_edges + e]], 1);
    }
}

// One-block exclusive scan over NN degrees -> row_ptr[NN+1]
__global__ __launch_bounds__(1024)
void scan_kernel(const int* __restrict__ deg, int* __restrict__ row_ptr, int n) {
    __shared__ int part[1024];
    const int t = threadIdx.x;
    const int chunk = (n + 1023) / 1024;
    int c0 = t * chunk;
    int c1 = min(c0 + chunk, n);
    int s = 0;
    for (int i = c0; i < c1; ++i) s += deg[i];
    part[t] = s;
    __syncthreads();
    for (int o = 1; o < 1024; o <<= 1) {
        int v = (t >= o) ? part[t - o] : 0;
        __syncthreads();
        part[t] += v;
        __syncthreads();
    }
    int excl = (t == 0) ? 0 : part[t - 1];
    for (int i = c0; i < c1; ++i) { row_ptr[i] = excl; excl += deg[i]; }
    if (t == 1023) row_ptr[n] = part[1023];
}

// cursor = row_ptr[0..n)
__global__ __launch_bounds__(256)
void copy_kernel(const int* __restrict__ src, int* __restrict__ dst, int n) {
    int t0 = blockIdx.x * blockDim.x + threadIdx.x;
    int stride = gridDim.x * blockDim.x;
    for (int i = t0; i < n; i += stride) dst[i] = src[i];
}

// sorted_src fill via atomic cursors
__global__ __launch_bounds__(256)
void fill_kernel(const int* __restrict__ ei, int* __restrict__ cursor,
                 int* __restrict__ ssrc, int n_edges) {
    int t0 = blockIdx.x * blockDim.x + threadIdx.x;
    int stride = gridDim.x * blockDim.x;
    for (int e = t0; e < n_edges; e += stride) {
        int s = ei[e];
        int d = ei[n_edges + e];
        int pos = atomicAdd(&cursor[d], 1);
        ssrc[pos] = s;
    }
}

// ---------------------------------------------------------------------------
// Gather aggregation: prop[n] = sum over edges of h[src]. One wave per node,
// lane covers float2 (64 lanes x 8B = full 512B row, coalesced).
// ---------------------------------------------------------------------------
__global__ __launch_bounds__(256)
void gather_kernel(const float* __restrict__ h, const int* __restrict__ rp,
                   const int* __restrict__ ssrc, float* __restrict__ prop,
                   int n_nodes) {
    int wid = (blockIdx.x * blockDim.x + threadIdx.x) >> 6;
    int lane = threadIdx.x & 63;
    if (wid >= n_nodes) return;
    int beg = rp[wid];
    int end = rp[wid + 1];
    float ax = 0.0f, ay = 0.0f;
    const float* hb = h + (size_t)lane * 2;
    int e = beg;
    for (; e + 1 < end; e += 2) {
        int s0 = ssrc[e];
        int s1 = ssrc[e + 1];
        float2 v0 = *reinterpret_cast<const float2*>(hb + (size_t)s0 * DD);
        float2 v1 = *reinterpret_cast<const float2*>(hb + (size_t)s1 * DD);
        ax += v0.x + v1.x;
        ay += v0.y + v1.y;
    }
    if (e < end) {
        int s0 = ssrc[e];
        float2 v0 = *reinterpret_cast<const float2*>(hb + (size_t)s0 * DD);
        ax += v0.x;
        ay += v0.y;
    }
    float2 r; r.x = ax; r.y = ay;
    *reinterpret_cast<float2*>(prop + (size_t)wid * DD + lane * 2) = r;
}

// ---------------------------------------------------------------------------
// Fused GEMM layer (unchanged from round 1):
//   DUAL=true : out = h @ W1^T + b1 + prop @ W2^T + b2, then L2-normalize+ReLU
//   DUAL=false: out = h @ W1^T + b1  (post1)
// NOTE: `out` may alias `prop` — each block stages its 4 rows into LDS before
// writing them, and rows are block-exclusive.
// ---------------------------------------------------------------------------
template<bool DUAL, bool NORM_RELU>
__global__ __launch_bounds__(512)
void gemm_kernel(const float* __restrict__ h, const float* __restrict__ prop,
                 const float* __restrict__ W1, const float* __restrict__ b1,
                 const float* __restrict__ W2, const float* __restrict__ b2,
                 float* __restrict__ out, int n_nodes) {
    __shared__ float w1_s[DD * 132];
    __shared__ float w2_s[DUAL ? DD * 132 : 4];
    __shared__ float h_s[4][DD];
    __shared__ float p_s[DUAL ? 4 : 1][DD];
    __shared__ float red_s[8];

    const int tid = threadIdx.x;

    {
        const float4* g1 = reinterpret_cast<const float4*>(W1);
        float4* s1 = reinterpret_cast<float4*>(w1_s);
        for (int j = tid; j < DD * 32; j += 512) {
            int r = j >> 5, c = j & 31;
            s1[r * 33 + c] = g1[j];
        }
        if (DUAL) {
            const float4* g2 = reinterpret_cast<const float4*>(W2);
            float4* s2 = reinterpret_cast<float4*>(w2_s);
            for (int j = tid; j < DD * 32; j += 512) {
                int r = j >> 5, c = j & 31;
                s2[r * 33 + c] = g2[j];
            }
        }
    }

    const int g = tid >> 7;    // node group within iteration (0..3)
    const int d = tid & 127;   // output dim
    float bias = b1[d] + (DUAL ? b2[d] : 0.0f);
    __syncthreads();

    const float4* w1_4 = reinterpret_cast<const float4*>(w1_s);
    const float4* w2_4 = DUAL ? reinterpret_cast<const float4*>(w2_s) : nullptr;

    for (int base = blockIdx.x * 4; base < n_nodes; base += gridDim.x * 4) {
        {
            int n_load = base + (tid >> 7);
            int k = tid & 127;
            if (n_load < n_nodes) {
                h_s[tid >> 7][k] = h[(size_t)n_load * DD + k];
                if (DUAL) p_s[tid >> 7][k] = prop[(size_t)n_load * DD + k];
            }
        }
        __syncthreads();

        const float4* hv4 = reinterpret_cast<const float4*>(h_s[g]);
        float acc1 = 0.0f, acc2 = 0.0f;
        #pragma unroll
        for (int c = 0; c < 32; ++c) {
            float4 hv = hv4[c];
            float4 wv = w1_4[d * 33 + c];
            acc1 += hv.x * wv.x + hv.y * wv.y + hv.z * wv.z + hv.w * wv.w;
            if (DUAL) {
                float4 pv = reinterpret_cast<const float4*>(p_s[g])[c];
                float4 w2v = w2_4[d * 33 + c];
                acc2 += pv.x * w2v.x + pv.y * w2v.y + pv.z * w2v.z + pv.w * w2v.w;
            }
        }
        float val = acc1 + acc2 + bias;

        int n = base + g;
        if (NORM_RELU) {
            float ss = val * val;
            #pragma unroll
            for (int o = 32; o > 0; o >>= 1) ss += __shfl_xor(ss, o);
            if ((tid & 63) == 0) red_s[tid >> 6] = ss;
            __syncthreads();
            float tot = red_s[g * 2] + red_s[g * 2 + 1];
            float norm = fmaxf(sqrtf(tot), 1e-12f);
            val = fmaxf(val / norm, 0.0f);
        }
        if (n < n_nodes) out[(size_t)n * DD + d] = val;
        __syncthreads();
    }
}

// ---------------------------------------------------------------------------
// Post2 + log_softmax (unchanged from round 1)
// ---------------------------------------------------------------------------
__global__ __launch_bounds__(256)
void post2_kernel(const float* __restrict__ hin, const float* __restrict__ W2,
                  const float* __restrict__ b2, float* __restrict__ out,
                  int n_nodes) {
    __shared__ float w_s[40 * 132];
    __shared__ float row_s[4][DD];
    const int tid = threadIdx.x;

    {
        const float4* gw = reinterpret_cast<const float4*>(W2);
        float4* sw = reinterpret_cast<float4*>(w_s);
        for (int j = tid; j < 40 * 32; j += 256) {
            int r = j >> 5, c = j & 31;
            sw[r * 33 + c] = gw[j];
        }
    }
    __syncthreads();

    const int wave = tid >> 6;
    const int lane = tid & 63;
    const float4* w4 = reinterpret_cast<const float4*>(w_s);
    const int lr = (lane < 40) ? lane : 0;
    const float bias = (lane < 40) ? b2[lr] : 0.0f;

    for (int base = blockIdx.x * 4; base < n_nodes; base += gridDim.x * 4) {
        int n = base + wave;
        bool alive = (n < n_nodes);
        if (alive) {
            row_s[wave][lane] = hin[(size_t)n * DD + lane];
            row_s[wave][64 + lane] = hin[(size_t)n * DD + 64 + lane];
        }
        __syncthreads();

        float acc = bias;
        const float4* r4 = reinterpret_cast<const float4*>(row_s[wave]);
        #pragma unroll
        for (int c = 0; c < 32; ++c) {
            float4 rv = r4[c];
            float4 wv = w4[lr * 33 + c];
            acc += rv.x * wv.x + rv.y * wv.y + rv.z * wv.z + rv.w * wv.w;
        }

        float m = (alive && lane < 40) ? acc : -INFINITY;
        #pragma unroll
        for (int o = 32; o > 0; o >>= 1) m = fmaxf(m, __shfl_xor(m, o));
        float e = (alive && lane < 40) ? expf(acc - m) : 0.0f;
        #pragma unroll
        for (int o = 32; o > 0; o >>= 1) e += __shfl_xor(e, o);

        if (alive && lane < 40) out[(size_t)n * 40 + lane] = acc - m - logf(e);
        __syncthreads();
    }
}

// ---------------------------------------------------------------------------
extern "C" void kernel_launch(void* const* d_in, const int* in_sizes, int n_in,
                              void* d_out, int out_size, void* d_ws, size_t ws_size,
                              hipStream_t stream) {
    const float* x  = (const float*)d_in[0];
    const int*   ei = (const int*)d_in[1];
    const float* Wl = (const float*)d_in[2];
    const float* bl = (const float*)d_in[3];
    const float* Wr = (const float*)d_in[4];
    const float* br = (const float*)d_in[5];
    const float* W1 = (const float*)d_in[6];
    const float* b1 = (const float*)d_in[7];
    const float* W2 = (const float*)d_in[8];
    const float* b2 = (const float*)d_in[9];
    float* outp = (float*)d_out;

    // Workspace layout: hA | hB | deg/cursor | row_ptr | sorted_src
    float* hA = (float*)d_ws;
    float* hB = hA + (size_t)NN * DD;
    int* deg = (int*)(hB + (size_t)NN * DD);   // also reused as cursor
    int* row_ptr = deg + NN;
    int* ssrc = row_ptr + NN + 1;

    // --- Build CSR (once per call; edge_index is layer-invariant) ---
    hipMemsetAsync(deg, 0, NN * sizeof(int), stream);
    deg_kernel<<<2048, 256, 0, stream>>>(ei, deg, NE);
    scan_kernel<<<1, 1024, 0, stream>>>(deg, row_ptr, NN);
    copy_kernel<<<128, 256, 0, stream>>>(row_ptr, deg, NN);   // deg -> cursor
    fill_kernel<<<2048, 256, 0, stream>>>(ei, deg, ssrc, NE);

    // --- Layers. Aliasing: gemm `out` overwrites its own `prop` input. ---
    const int gather_grid = (NN * 64 + 255) / 256;
    const float* hcur = x;
    float* prop;
    for (int i = 0; i < 3; ++i) {
        prop = (i == 0) ? hA : ((hcur == hA) ? hB : hA);
        gather_kernel<<<gather_grid, 256, 0, stream>>>(hcur, row_ptr, ssrc, prop, NN);
        gemm_kernel<true, true><<<256, 512, 0, stream>>>(
            hcur, prop,
            Wl + (size_t)i * DD * DD, bl + (size_t)i * DD,
            Wr + (size_t)i * DD * DD, br + (size_t)i * DD,
            prop, NN);   // out aliases prop (safe: rows staged per-block)
        hcur = prop;
    }
    float* post1_out = (hcur == hA) ? hB : hA;
    gemm_kernel<false, false><<<512, 512, 0, stream>>>(
        hcur, nullptr, W1, b1, nullptr, nullptr, post1_out, NN);
    post2_kernel<<<1024, 256, 0, stream>>>(post1_out, W2, b2, outp, NN);
}

// Round 3
// 869.713 us; speedup vs baseline: 10.4932x; 1.9551x over previous
//
#include <hip/hip_runtime.h>
#include <hip/hip_bf16.h>
#include <cstdint>
#include <cstddef>

#define NN 100000
#define DD 128
#define NE 1600000

typedef short bf16x8 __attribute__((ext_vector_type(8)));
typedef float f32x4 __attribute__((ext_vector_type(4)));
typedef unsigned short u16;
typedef unsigned int u32;

__device__ inline float b2f(u16 u) {
    union { u32 i; float f; } c; c.i = ((u32)u) << 16; return c.f;
}
__device__ inline u16 f2b(float f) {
    __hip_bfloat16 h = __float2bfloat16(f);   // RNE
    return *reinterpret_cast<u16*>(&h);
}

// ---------------------------------------------------------------------------
// CSR build
// ---------------------------------------------------------------------------
__global__ __launch_bounds__(256)
void deg_kernel(const int* __restrict__ ei, int* __restrict__ deg, int n_edges) {
    int t0 = blockIdx.x * blockDim.x + threadIdx.x;
    int stride = gridDim.x * blockDim.x;
    for (int e = t0; e < n_edges; e += stride) atomicAdd(&deg[ei[n_edges + e]], 1);
}

__global__ __launch_bounds__(1024)
void scan_kernel(const int* __restrict__ deg, int* __restrict__ row_ptr, int n) {
    __shared__ int part[1024];
    const int t = threadIdx.x;
    const int chunk = (n + 1023) / 1024;
    int c0 = t * chunk, c1 = min(c0 + chunk, n);
    int s = 0;
    for (int i = c0; i < c1; ++i) s += deg[i];
    part[t] = s;
    __syncthreads();
    for (int o = 1; o < 1024; o <<= 1) {
        int v = (t >= o) ? part[t - o] : 0;
        __syncthreads();
        part[t] += v;
        __syncthreads();
    }
    int excl = (t == 0) ? 0 : part[t - 1];
    for (int i = c0; i < c1; ++i) { row_ptr[i] = excl; excl += deg[i]; }
    if (t == 1023) row_ptr[n] = part[1023];
}

__global__ __launch_bounds__(256)
void copy_kernel(const int* __restrict__ src, int* __restrict__ dst, int n) {
    int t0 = blockIdx.x * blockDim.x + threadIdx.x;
    int stride = gridDim.x * blockDim.x;
    for (int i = t0; i < n; i += stride) dst[i] = src[i];
}

__global__ __launch_bounds__(256)
void fill_kernel(const int* __restrict__ ei, int* __restrict__ cursor,
                 int* __restrict__ ssrc, int n_edges) {
    int t0 = blockIdx.x * blockDim.x + threadIdx.x;
    int stride = gridDim.x * blockDim.x;
    for (int e = t0; e < n_edges; e += stride) {
        int s = ei[e];
        int d = ei[n_edges + e];
        int pos = atomicAdd(&cursor[d], 1);
        ssrc[pos] = s;
    }
}

// ---------------------------------------------------------------------------
// Conversions
// ---------------------------------------------------------------------------
__global__ __launch_bounds__(256)
void cvt_x_kernel(const float* __restrict__ x, u16* __restrict__ xb, long long n4) {
    long long t = (long long)blockIdx.x * blockDim.x + threadIdx.x;
    long long stride = (long long)gridDim.x * blockDim.x;
    for (; t < n4; t += stride) {
        float4 v = reinterpret_cast<const float4*>(x)[t];
        ushort4 o;
        o.x = f2b(v.x); o.y = f2b(v.y); o.z = f2b(v.z); o.w = f2b(v.w);
        reinterpret_cast<ushort4*>(xb)[t] = o;
    }
}

// Wcat[l][d][k] (k<128 from Wl, else Wr), then Wp1[d][k] from W_post1.
__global__ __launch_bounds__(256)
void cvt_w_kernel(const float* __restrict__ Wl, const float* __restrict__ Wr,
                  const float* __restrict__ Wp1f, u16* __restrict__ Wcat,
                  u16* __restrict__ Wp1) {
    int t = blockIdx.x * blockDim.x + threadIdx.x;
    const int NCAT = 3 * 128 * 256;
    if (t < NCAT) {
        int layer = t >> 15;          // /32768
        int rem = t & 32767;
        int d = rem >> 8;
        int k = rem & 255;
        float v = (k < 128) ? Wl[layer * 16384 + d * 128 + k]
                            : Wr[layer * 16384 + d * 128 + (k - 128)];
        Wcat[t] = f2b(v);
    } else if (t < NCAT + 128 * 128) {
        int i = t - NCAT;
        Wp1[i] = f2b(Wp1f[i]);
    }
}

// ---------------------------------------------------------------------------
// Gather aggregation (bf16 in, bf16 out, fp32 accum). One wave per node;
// lane covers 2 elems (64 lanes x 4B = full 256B bf16 row, coalesced).
// ---------------------------------------------------------------------------
__global__ __launch_bounds__(256)
void gather_kernel(const u16* __restrict__ h, const int* __restrict__ rp,
                   const int* __restrict__ ssrc, u16* __restrict__ prop,
                   int n_nodes) {
    int wid = (blockIdx.x * blockDim.x + threadIdx.x) >> 6;
    int lane = threadIdx.x & 63;
    if (wid >= n_nodes) return;
    int beg = rp[wid], end = rp[wid + 1];
    float ax = 0.0f, ay = 0.0f;
    const u16* hb = h + lane * 2;
    int e = beg;
    for (; e + 1 < end; e += 2) {
        int s0 = ssrc[e];
        int s1 = ssrc[e + 1];
        u32 v0 = *reinterpret_cast<const u32*>(hb + (size_t)s0 * DD);
        u32 v1 = *reinterpret_cast<const u32*>(hb + (size_t)s1 * DD);
        union { u32 i; float f; } c;
        c.i = v0 << 16; ax += c.f;
        c.i = v0 & 0xffff0000u; ay += c.f;
        c.i = v1 << 16; ax += c.f;
        c.i = v1 & 0xffff0000u; ay += c.f;
    }
    if (e < end) {
        u32 v0 = *reinterpret_cast<const u32*>(hb + (size_t)ssrc[e] * DD);
        union { u32 i; float f; } c;
        c.i = v0 << 16; ax += c.f;
        c.i = v0 & 0xffff0000u; ay += c.f;
    }
    u32 o = (u32)f2b(ax) | ((u32)f2b(ay) << 16);
    *reinterpret_cast<u32*>(prop + (size_t)wid * DD + lane * 2) = o;
}

// ---------------------------------------------------------------------------
// MFMA layer GEMM.
//   KSTEPS=8, DUAL_NORM=true : out = normalize_relu([h|prop] @ Wcat^T + b1+b2)
//   KSTEPS=4, DUAL_NORM=false: out = h @ Wp1^T + b1
// Block: 256 thr = 4 waves; strip of 32 nodes; wave w owns cols [32w,32w+32).
// B-frags in registers (loaded once); A-tile in LDS, 16B-chunk XOR swizzle.
// ---------------------------------------------------------------------------
template<int KSTEPS, bool DUAL_NORM>
__global__ __launch_bounds__(256)
void mfma_layer(const u16* __restrict__ hin, const u16* __restrict__ prop,
                const u16* __restrict__ Wc, const float* __restrict__ b1,
                const float* __restrict__ b2, u16* __restrict__ out,
                int n_strips) {
    constexpr int ROWB = KSTEPS * 64;   // bytes per A row in LDS (512 / 256)
    constexpr int CPR = KSTEPS * 4;     // 16B chunks per row (32 / 16)
    constexpr int KTOT = KSTEPS * 32;   // 256 / 128
    __shared__ char a_s[32 * ROWB];
    __shared__ float red_s[32][4];

    const int tid = threadIdx.x;
    const int w = tid >> 6;
    const int l = tid & 63;
    const int q = l >> 4;     // quad 0..3 (k-group / output row group)
    const int c16 = l & 15;   // col within 16-wide tile

    // B fragments: cols col[t] = w*32 + t*16 + c16, k = kk*32 + q*8 .. +8
    bf16x8 bfrag[2][KSTEPS];
    int col[2];
    float bias[2];
    #pragma unroll
    for (int t = 0; t < 2; ++t) {
        col[t] = w * 32 + t * 16 + c16;
        bias[t] = b1[col[t]] + (DUAL_NORM ? b2[col[t]] : 0.0f);
        #pragma unroll
        for (int kk = 0; kk < KSTEPS; ++kk)
            bfrag[t][kk] = *reinterpret_cast<const bf16x8*>(
                Wc + (size_t)col[t] * KTOT + kk * 32 + q * 8);
    }

    for (int strip = blockIdx.x; strip < n_strips; strip += gridDim.x) {
        const int base = strip * 32;

        // Stage A tile: 32 rows x ROWB bytes, chunk-swizzled (c ^= r&7).
        for (int ci = tid; ci < 32 * CPR; ci += 256) {
            int r = ci / CPR, c = ci % CPR;
            const u16* src;
            int node = base + r;
            if (DUAL_NORM)
                src = (c < 16) ? (hin + (size_t)node * DD + c * 8)
                               : (prop + (size_t)node * DD + (c - 16) * 8);
            else
                src = hin + (size_t)node * DD + c * 8;
            *reinterpret_cast<uint4*>(a_s + r * ROWB + ((c ^ (r & 7)) * 16)) =
                *reinterpret_cast<const uint4*>(src);
        }
        __syncthreads();

        f32x4 acc[2][2] = {};   // [mtile][ntile]
        #pragma unroll
        for (int kk = 0; kk < KSTEPS; ++kk) {
            int cc = kk * 4 + q;
            bf16x8 a0 = *reinterpret_cast<const bf16x8*>(
                a_s + c16 * ROWB + ((cc ^ (c16 & 7)) * 16));
            bf16x8 a1 = *reinterpret_cast<const bf16x8*>(
                a_s + (16 + c16) * ROWB + ((cc ^ ((16 + c16) & 7)) * 16));
            acc[0][0] = __builtin_amdgcn_mfma_f32_16x16x32_bf16(a0, bfrag[0][kk], acc[0][0], 0, 0, 0);
            acc[0][1] = __builtin_amdgcn_mfma_f32_16x16x32_bf16(a0, bfrag[1][kk], acc[0][1], 0, 0, 0);
            acc[1][0] = __builtin_amdgcn_mfma_f32_16x16x32_bf16(a1, bfrag[0][kk], acc[1][0], 0, 0, 0);
            acc[1][1] = __builtin_amdgcn_mfma_f32_16x16x32_bf16(a1, bfrag[1][kk], acc[1][1], 0, 0, 0);
        }

        if (DUAL_NORM) {
            float vals[2][2][4];
            float ss[2][4];
            #pragma unroll
            for (int m = 0; m < 2; ++m) {
                #pragma unroll
                for (int reg = 0; reg < 4; ++reg) {
                    float s = 0.0f;
                    #pragma unroll
                    for (int t = 0; t < 2; ++t) {
                        float v = acc[m][t][reg] + bias[t];
                        vals[m][t][reg] = v;
                        s += v * v;
                    }
                    s += __shfl_xor(s, 1);
                    s += __shfl_xor(s, 2);
                    s += __shfl_xor(s, 4);
                    s += __shfl_xor(s, 8);
                    ss[m][reg] = s;
                }
            }
            if (c16 == 0) {
                #pragma unroll
                for (int m = 0; m < 2; ++m)
                    #pragma unroll
                    for (int reg = 0; reg < 4; ++reg)
                        red_s[m * 16 + q * 4 + reg][w] = ss[m][reg];
            }
            __syncthreads();
            #pragma unroll
            for (int m = 0; m < 2; ++m) {
                #pragma unroll
                for (int reg = 0; reg < 4; ++reg) {
                    int row = m * 16 + q * 4 + reg;
                    float4 rr = *reinterpret_cast<float4*>(&red_s[row][0]);
                    float tot = rr.x + rr.y + rr.z + rr.w;
                    float rn = 1.0f / fmaxf(sqrtf(tot), 1e-12f);
                    #pragma unroll
                    for (int t = 0; t < 2; ++t) {
                        float v = fmaxf(vals[m][t][reg] * rn, 0.0f);
                        out[(size_t)(base + row) * DD + col[t]] = f2b(v);
                    }
                }
            }
            __syncthreads();   // red_s/a_s safe before next strip
        } else {
            #pragma unroll
            for (int m = 0; m < 2; ++m)
                #pragma unroll
                for (int reg = 0; reg < 4; ++reg) {
                    int row = m * 16 + q * 4 + reg;
                    #pragma unroll
                    for (int t = 0; t < 2; ++t) {
                        float v = acc[m][t][reg] + bias[t];
                        out[(size_t)(base + row) * DD + col[t]] = f2b(v);
                    }
                }
            __syncthreads();   // a_s safe before next strip
        }
    }
}

// ---------------------------------------------------------------------------
// Post2 + log_softmax: out[n][l] = log_softmax(hin[n] @ W2^T + b2). bf16 in,
// fp32 math/out. One wave per node.
// ---------------------------------------------------------------------------
__global__ __launch_bounds__(256)
void post2_kernel(const u16* __restrict__ hin, const float* __restrict__ W2,
                  const float* __restrict__ b2, float* __restrict__ out,
                  int n_nodes) {
    __shared__ float w_s[40 * 132];
    __shared__ float row_s[4][DD];
    const int tid = threadIdx.x;

    {
        const float4* gw = reinterpret_cast<const float4*>(W2);
        float4* sw = reinterpret_cast<float4*>(w_s);
        for (int j = tid; j < 40 * 32; j += 256) {
            int r = j >> 5, c = j & 31;
            sw[r * 33 + c] = gw[j];
        }
    }
    __syncthreads();

    const int wave = tid >> 6;
    const int lane = tid & 63;
    const float4* w4 = reinterpret_cast<const float4*>(w_s);
    const int lr = (lane < 40) ? lane : 0;
    const float bias = (lane < 40) ? b2[lr] : 0.0f;

    for (int base = blockIdx.x * 4; base < n_nodes; base += gridDim.x * 4) {
        int n = base + wave;
        bool alive = (n < n_nodes);
        if (alive) {
            row_s[wave][lane] = b2f(hin[(size_t)n * DD + lane]);
            row_s[wave][64 + lane] = b2f(hin[(size_t)n * DD + 64 + lane]);
        }
        __syncthreads();

        float acc = bias;
        const float4* r4 = reinterpret_cast<const float4*>(row_s[wave]);
        #pragma unroll
        for (int c = 0; c < 32; ++c) {
            float4 rv = r4[c];
            float4 wv = w4[lr * 33 + c];
            acc += rv.x * wv.x + rv.y * wv.y + rv.z * wv.z + rv.w * wv.w;
        }

        float m = (alive && lane < 40) ? acc : -INFINITY;
        #pragma unroll
        for (int o = 32; o > 0; o >>= 1) m = fmaxf(m, __shfl_xor(m, o));
        float e = (alive && lane < 40) ? expf(acc - m) : 0.0f;
        #pragma unroll
        for (int o = 32; o > 0; o >>= 1) e += __shfl_xor(e, o);

        if (alive && lane < 40) out[(size_t)n * 40 + lane] = acc - m - logf(e);
        __syncthreads();
    }
}

// ---------------------------------------------------------------------------
extern "C" void kernel_launch(void* const* d_in, const int* in_sizes, int n_in,
                              void* d_out, int out_size, void* d_ws, size_t ws_size,
                              hipStream_t stream) {
    const float* x   = (const float*)d_in[0];
    const int*   ei  = (const int*)d_in[1];
    const float* Wl  = (const float*)d_in[2];
    const float* bl  = (const float*)d_in[3];
    const float* Wr  = (const float*)d_in[4];
    const float* br  = (const float*)d_in[5];
    const float* W1f = (const float*)d_in[6];
    const float* b1  = (const float*)d_in[7];
    const float* W2  = (const float*)d_in[8];
    const float* b2  = (const float*)d_in[9];
    float* outp = (float*)d_out;

    // Workspace: xb | P | bufA | bufB | Wcat | Wp1 | deg | row_ptr | ssrc
    u16* xb   = (u16*)d_ws;
    u16* P    = xb + (size_t)NN * DD;
    u16* bufA = P + (size_t)NN * DD;
    u16* bufB = bufA + (size_t)NN * DD;
    u16* Wcat = bufB + (size_t)NN * DD;
    u16* Wp1  = Wcat + 3 * 128 * 256;
    int* deg     = (int*)(Wp1 + 128 * 128);
    int* row_ptr = deg + NN;
    int* ssrc    = row_ptr + NN + 1;

    // CSR build
    hipMemsetAsync(deg, 0, NN * sizeof(int), stream);
    deg_kernel<<<2048, 256, 0, stream>>>(ei, deg, NE);
    scan_kernel<<<1, 1024, 0, stream>>>(deg, row_ptr, NN);
    copy_kernel<<<128, 256, 0, stream>>>(row_ptr, deg, NN);
    fill_kernel<<<2048, 256, 0, stream>>>(ei, deg, ssrc, NE);

    // Conversions
    cvt_x_kernel<<<12500, 256, 0, stream>>>(x, xb, (long long)NN * DD / 4);
    cvt_w_kernel<<<(3 * 128 * 256 + 128 * 128 + 255) / 256, 256, 0, stream>>>(
        Wl, Wr, W1f, Wcat, Wp1);

    const int n_strips = NN / 32;   // 3125 exactly
    const int gather_grid = (NN * 64 + 255) / 256;

    const u16* hcur = xb;
    u16* hnext;
    for (int i = 0; i < 3; ++i) {
        hnext = (i == 0) ? bufA : ((hcur == bufA) ? bufB : bufA);
        gather_kernel<<<gather_grid, 256, 0, stream>>>(hcur, row_ptr, ssrc, P, NN);
        mfma_layer<8, true><<<n_strips, 256, 0, stream>>>(
            hcur, P, Wcat + (size_t)i * 128 * 256,
            bl + (size_t)i * DD, br + (size_t)i * DD, hnext, n_strips);
        hcur = hnext;
    }
    u16* p1out = (hcur == bufA) ? bufB : bufA;
    mfma_layer<4, false><<<n_strips, 256, 0, stream>>>(
        hcur, nullptr, Wp1, b1, nullptr, p1out, n_strips);
    post2_kernel<<<1024, 256, 0, stream>>>(p1out, W2, b2, outp, NN);
}

// Round 4
// 722.257 us; speedup vs baseline: 12.6354x; 1.2042x over previous
//
#include <hip/hip_runtime.h>
#include <hip/hip_bf16.h>
#include <cstdint>
#include <cstddef>

#define NN 100000
#define DD 128
#define NE 1600000

typedef short bf16x8 __attribute__((ext_vector_type(8)));
typedef float f32x4 __attribute__((ext_vector_type(4)));
typedef unsigned short u16;
typedef unsigned int u32;

__device__ inline float b2f(u16 u) {
    union { u32 i; float f; } c; c.i = ((u32)u) << 16; return c.f;
}
__device__ inline u16 f2b(float f) {
    __hip_bfloat16 h = __float2bfloat16(f);   // RNE
    return *reinterpret_cast<u16*>(&h);
}

// ---------------------------------------------------------------------------
// CSR build: degree histogram over dst
// ---------------------------------------------------------------------------
__global__ __launch_bounds__(256)
void deg_kernel(const int* __restrict__ ei, int* __restrict__ deg, int n_edges) {
    int t0 = blockIdx.x * blockDim.x + threadIdx.x;
    int stride = gridDim.x * blockDim.x;
    for (int e = t0; e < n_edges; e += stride) atomicAdd(&deg[ei[n_edges + e]], 1);
}

// --- Two-level parallel exclusive scan over NN degrees ---------------------
// Level 1: per-block (1024-elem) sums.
__global__ __launch_bounds__(1024)
void psum_kernel(const int* __restrict__ deg, int* __restrict__ bsum, int n) {
    __shared__ int ws[16];
    int i = blockIdx.x * 1024 + threadIdx.x;
    int lane = threadIdx.x & 63, wv = threadIdx.x >> 6;
    int v = (i < n) ? deg[i] : 0;
    #pragma unroll
    for (int o = 32; o > 0; o >>= 1) v += __shfl_xor(v, o);
    if (lane == 0) ws[wv] = v;
    __syncthreads();
    if (threadIdx.x == 0) {
        int s = 0;
        #pragma unroll
        for (int k = 0; k < 16; ++k) s += ws[k];
        bsum[blockIdx.x] = s;
    }
}

// Level 2: single small block scans the partials in-place (exclusive).
__global__ __launch_bounds__(128)
void scan_bsum_kernel(int* __restrict__ bsum, int nb) {
    __shared__ int tmp[128];
    int t = threadIdx.x;
    int v = (t < nb) ? bsum[t] : 0;
    tmp[t] = v;
    __syncthreads();
    for (int o = 1; o < 128; o <<= 1) {
        int u = (t >= o) ? tmp[t - o] : 0;
        __syncthreads();
        tmp[t] += u;
        __syncthreads();
    }
    if (t < nb) bsum[t] = tmp[t] - v;   // exclusive
}

// Level 3: in-block exclusive scan + block offset -> row_ptr (and row_ptr[n]).
__global__ __launch_bounds__(1024)
void emit_kernel(const int* __restrict__ deg, const int* __restrict__ bsum,
                 int* __restrict__ row_ptr, int n) {
    __shared__ int ws[16];
    __shared__ int wexc[16];
    int i = blockIdx.x * 1024 + threadIdx.x;
    int lane = threadIdx.x & 63, wv = threadIdx.x >> 6;
    int v = (i < n) ? deg[i] : 0;
    int inc = v;
    #pragma unroll
    for (int o = 1; o < 64; o <<= 1) {
        int t = __shfl_up(inc, o);
        if (lane >= o) inc += t;
    }
    if (lane == 63) ws[wv] = inc;
    __syncthreads();
    if (threadIdx.x == 0) {
        int s = 0;
        #pragma unroll
        for (int k = 0; k < 16; ++k) { wexc[k] = s; s += ws[k]; }
    }
    __syncthreads();
    int excl = inc - v + wexc[wv] + bsum[blockIdx.x];
    if (i < n) {
        row_ptr[i] = excl;
        if (i == n - 1) row_ptr[n] = excl + v;
    }
}

__global__ __launch_bounds__(256)
void copy_kernel(const int* __restrict__ src, int* __restrict__ dst, int n) {
    int t0 = blockIdx.x * blockDim.x + threadIdx.x;
    int stride = gridDim.x * blockDim.x;
    for (int i = t0; i < n; i += stride) dst[i] = src[i];
}

__global__ __launch_bounds__(256)
void fill_kernel(const int* __restrict__ ei, int* __restrict__ cursor,
                 int* __restrict__ ssrc, int n_edges) {
    int t0 = blockIdx.x * blockDim.x + threadIdx.x;
    int stride = gridDim.x * blockDim.x;
    for (int e = t0; e < n_edges; e += stride) {
        int s = ei[e];
        int d = ei[n_edges + e];
        int pos = atomicAdd(&cursor[d], 1);
        ssrc[pos] = s;
    }
}

// ---------------------------------------------------------------------------
// Conversions
// ---------------------------------------------------------------------------
__global__ __launch_bounds__(256)
void cvt_x_kernel(const float* __restrict__ x, u16* __restrict__ xb, long long n4) {
    long long t = (long long)blockIdx.x * blockDim.x + threadIdx.x;
    long long stride = (long long)gridDim.x * blockDim.x;
    for (; t < n4; t += stride) {
        float4 v = reinterpret_cast<const float4*>(x)[t];
        ushort4 o;
        o.x = f2b(v.x); o.y = f2b(v.y); o.z = f2b(v.z); o.w = f2b(v.w);
        reinterpret_cast<ushort4*>(xb)[t] = o;
    }
}

// Wcat[l][d][k] (k<128 from Wl, else Wr), then Wp1[d][k] from W_post1.
__global__ __launch_bounds__(256)
void cvt_w_kernel(const float* __restrict__ Wl, const float* __restrict__ Wr,
                  const float* __restrict__ Wp1f, u16* __restrict__ Wcat,
                  u16* __restrict__ Wp1) {
    int t = blockIdx.x * blockDim.x + threadIdx.x;
    const int NCAT = 3 * 128 * 256;
    if (t < NCAT) {
        int layer = t >> 15;
        int rem = t & 32767;
        int d = rem >> 8;
        int k = rem & 255;
        float v = (k < 128) ? Wl[layer * 16384 + d * 128 + k]
                            : Wr[layer * 16384 + d * 128 + (k - 128)];
        Wcat[t] = f2b(v);
    } else if (t < NCAT + 128 * 128) {
        int i = t - NCAT;
        Wp1[i] = f2b(Wp1f[i]);
    }
}

// ---------------------------------------------------------------------------
// Gather aggregation (bf16 in, bf16 out, fp32 accum). One wave per node.
// ---------------------------------------------------------------------------
__global__ __launch_bounds__(256)
void gather_kernel(const u16* __restrict__ h, const int* __restrict__ rp,
                   const int* __restrict__ ssrc, u16* __restrict__ prop,
                   int n_nodes) {
    int wid = (blockIdx.x * blockDim.x + threadIdx.x) >> 6;
    int lane = threadIdx.x & 63;
    if (wid >= n_nodes) return;
    int beg = rp[wid], end = rp[wid + 1];
    float ax = 0.0f, ay = 0.0f;
    const u16* hb = h + lane * 2;
    int e = beg;
    for (; e + 1 < end; e += 2) {
        int s0 = ssrc[e];
        int s1 = ssrc[e + 1];
        u32 v0 = *reinterpret_cast<const u32*>(hb + (size_t)s0 * DD);
        u32 v1 = *reinterpret_cast<const u32*>(hb + (size_t)s1 * DD);
        union { u32 i; float f; } c;
        c.i = v0 << 16; ax += c.f;
        c.i = v0 & 0xffff0000u; ay += c.f;
        c.i = v1 << 16; ax += c.f;
        c.i = v1 & 0xffff0000u; ay += c.f;
    }
    if (e < end) {
        u32 v0 = *reinterpret_cast<const u32*>(hb + (size_t)ssrc[e] * DD);
        union { u32 i; float f; } c;
        c.i = v0 << 16; ax += c.f;
        c.i = v0 & 0xffff0000u; ay += c.f;
    }
    u32 o = (u32)f2b(ax) | ((u32)f2b(ay) << 16);
    *reinterpret_cast<u32*>(prop + (size_t)wid * DD + lane * 2) = o;
}

// ---------------------------------------------------------------------------
// MFMA layer GEMM (unchanged from round 3).
// ---------------------------------------------------------------------------
template<int KSTEPS, bool DUAL_NORM>
__global__ __launch_bounds__(256)
void mfma_layer(const u16* __restrict__ hin, const u16* __restrict__ prop,
                const u16* __restrict__ Wc, const float* __restrict__ b1,
                const float* __restrict__ b2, u16* __restrict__ out,
                int n_strips) {
    constexpr int ROWB = KSTEPS * 64;
    constexpr int CPR = KSTEPS * 4;
    constexpr int KTOT = KSTEPS * 32;
    __shared__ char a_s[32 * ROWB];
    __shared__ float red_s[32][4];

    const int tid = threadIdx.x;
    const int w = tid >> 6;
    const int l = tid & 63;
    const int q = l >> 4;
    const int c16 = l & 15;

    bf16x8 bfrag[2][KSTEPS];
    int col[2];
    float bias[2];
    #pragma unroll
    for (int t = 0; t < 2; ++t) {
        col[t] = w * 32 + t * 16 + c16;
        bias[t] = b1[col[t]] + (DUAL_NORM ? b2[col[t]] : 0.0f);
        #pragma unroll
        for (int kk = 0; kk < KSTEPS; ++kk)
            bfrag[t][kk] = *reinterpret_cast<const bf16x8*>(
                Wc + (size_t)col[t] * KTOT + kk * 32 + q * 8);
    }

    for (int strip = blockIdx.x; strip < n_strips; strip += gridDim.x) {
        const int base = strip * 32;

        for (int ci = tid; ci < 32 * CPR; ci += 256) {
            int r = ci / CPR, c = ci % CPR;
            const u16* src;
            int node = base + r;
            if (DUAL_NORM)
                src = (c < 16) ? (hin + (size_t)node * DD + c * 8)
                               : (prop + (size_t)node * DD + (c - 16) * 8);
            else
                src = hin + (size_t)node * DD + c * 8;
            *reinterpret_cast<uint4*>(a_s + r * ROWB + ((c ^ (r & 7)) * 16)) =
                *reinterpret_cast<const uint4*>(src);
        }
        __syncthreads();

        f32x4 acc[2][2] = {};
        #pragma unroll
        for (int kk = 0; kk < KSTEPS; ++kk) {
            int cc = kk * 4 + q;
            bf16x8 a0 = *reinterpret_cast<const bf16x8*>(
                a_s + c16 * ROWB + ((cc ^ (c16 & 7)) * 16));
            bf16x8 a1 = *reinterpret_cast<const bf16x8*>(
                a_s + (16 + c16) * ROWB + ((cc ^ ((16 + c16) & 7)) * 16));
            acc[0][0] = __builtin_amdgcn_mfma_f32_16x16x32_bf16(a0, bfrag[0][kk], acc[0][0], 0, 0, 0);
            acc[0][1] = __builtin_amdgcn_mfma_f32_16x16x32_bf16(a0, bfrag[1][kk], acc[0][1], 0, 0, 0);
            acc[1][0] = __builtin_amdgcn_mfma_f32_16x16x32_bf16(a1, bfrag[0][kk], acc[1][0], 0, 0, 0);
            acc[1][1] = __builtin_amdgcn_mfma_f32_16x16x32_bf16(a1, bfrag[1][kk], acc[1][1], 0, 0, 0);
        }

        if (DUAL_NORM) {
            float vals[2][2][4];
            float ss[2][4];
            #pragma unroll
            for (int m = 0; m < 2; ++m) {
                #pragma unroll
                for (int reg = 0; reg < 4; ++reg) {
                    float s = 0.0f;
                    #pragma unroll
                    for (int t = 0; t < 2; ++t) {
                        float v = acc[m][t][reg] + bias[t];
                        vals[m][t][reg] = v;
                        s += v * v;
                    }
                    s += __shfl_xor(s, 1);
                    s += __shfl_xor(s, 2);
                    s += __shfl_xor(s, 4);
                    s += __shfl_xor(s, 8);
                    ss[m][reg] = s;
                }
            }
            if (c16 == 0) {
                #pragma unroll
                for (int m = 0; m < 2; ++m)
                    #pragma unroll
                    for (int reg = 0; reg < 4; ++reg)
                        red_s[m * 16 + q * 4 + reg][w] = ss[m][reg];
            }
            __syncthreads();
            #pragma unroll
            for (int m = 0; m < 2; ++m) {
                #pragma unroll
                for (int reg = 0; reg < 4; ++reg) {
                    int row = m * 16 + q * 4 + reg;
                    float4 rr = *reinterpret_cast<float4*>(&red_s[row][0]);
                    float tot = rr.x + rr.y + rr.z + rr.w;
                    float rn = 1.0f / fmaxf(sqrtf(tot), 1e-12f);
                    #pragma unroll
                    for (int t = 0; t < 2; ++t) {
                        float v = fmaxf(vals[m][t][reg] * rn, 0.0f);
                        out[(size_t)(base + row) * DD + col[t]] = f2b(v);
                    }
                }
            }
            __syncthreads();
        } else {
            #pragma unroll
            for (int m = 0; m < 2; ++m)
                #pragma unroll
                for (int reg = 0; reg < 4; ++reg) {
                    int row = m * 16 + q * 4 + reg;
                    #pragma unroll
                    for (int t = 0; t < 2; ++t) {
                        float v = acc[m][t][reg] + bias[t];
                        out[(size_t)(base + row) * DD + col[t]] = f2b(v);
                    }
                }
            __syncthreads();
        }
    }
}

// ---------------------------------------------------------------------------
// Post2 + log_softmax (bf16 in, fp32 out)
// ---------------------------------------------------------------------------
__global__ __launch_bounds__(256)
void post2_kernel(const u16* __restrict__ hin, const float* __restrict__ W2,
                  const float* __restrict__ b2, float* __restrict__ out,
                  int n_nodes) {
    __shared__ float w_s[40 * 132];
    __shared__ float row_s[4][DD];
    const int tid = threadIdx.x;

    {
        const float4* gw = reinterpret_cast<const float4*>(W2);
        float4* sw = reinterpret_cast<float4*>(w_s);
        for (int j = tid; j < 40 * 32; j += 256) {
            int r = j >> 5, c = j & 31;
            sw[r * 33 + c] = gw[j];
        }
    }
    __syncthreads();

    const int wave = tid >> 6;
    const int lane = tid & 63;
    const float4* w4 = reinterpret_cast<const float4*>(w_s);
    const int lr = (lane < 40) ? lane : 0;
    const float bias = (lane < 40) ? b2[lr] : 0.0f;

    for (int base = blockIdx.x * 4; base < n_nodes; base += gridDim.x * 4) {
        int n = base + wave;
        bool alive = (n < n_nodes);
        if (alive) {
            row_s[wave][lane] = b2f(hin[(size_t)n * DD + lane]);
            row_s[wave][64 + lane] = b2f(hin[(size_t)n * DD + 64 + lane]);
        }
        __syncthreads();

        float acc = bias;
        const float4* r4 = reinterpret_cast<const float4*>(row_s[wave]);
        #pragma unroll
        for (int c = 0; c < 32; ++c) {
            float4 rv = r4[c];
            float4 wv = w4[lr * 33 + c];
            acc += rv.x * wv.x + rv.y * wv.y + rv.z * wv.z + rv.w * wv.w;
        }

        float m = (alive && lane < 40) ? acc : -INFINITY;
        #pragma unroll
        for (int o = 32; o > 0; o >>= 1) m = fmaxf(m, __shfl_xor(m, o));
        float e = (alive && lane < 40) ? expf(acc - m) : 0.0f;
        #pragma unroll
        for (int o = 32; o > 0; o >>= 1) e += __shfl_xor(e, o);

        if (alive && lane < 40) out[(size_t)n * 40 + lane] = acc - m - logf(e);
        __syncthreads();
    }
}

// ---------------------------------------------------------------------------
extern "C" void kernel_launch(void* const* d_in, const int* in_sizes, int n_in,
                              void* d_out, int out_size, void* d_ws, size_t ws_size,
                              hipStream_t stream) {
    const float* x   = (const float*)d_in[0];
    const int*   ei  = (const int*)d_in[1];
    const float* Wl  = (const float*)d_in[2];
    const float* bl  = (const float*)d_in[3];
    const float* Wr  = (const float*)d_in[4];
    const float* br  = (const float*)d_in[5];
    const float* W1f = (const float*)d_in[6];
    const float* b1  = (const float*)d_in[7];
    const float* W2  = (const float*)d_in[8];
    const float* b2  = (const float*)d_in[9];
    float* outp = (float*)d_out;

    // Workspace: xb | P | bufA | bufB | Wcat | Wp1 | deg | row_ptr | ssrc | bsum
    u16* xb   = (u16*)d_ws;
    u16* P    = xb + (size_t)NN * DD;
    u16* bufA = P + (size_t)NN * DD;
    u16* bufB = bufA + (size_t)NN * DD;
    u16* Wcat = bufB + (size_t)NN * DD;
    u16* Wp1  = Wcat + 3 * 128 * 256;
    int* deg     = (int*)(Wp1 + 128 * 128);
    int* row_ptr = deg + NN;
    int* ssrc    = row_ptr + NN + 1;
    int* bsum    = ssrc + NE;

    const int NB = (NN + 1023) / 1024;   // 98

    // CSR build (parallel scan)
    hipMemsetAsync(deg, 0, NN * sizeof(int), stream);
    deg_kernel<<<2048, 256, 0, stream>>>(ei, deg, NE);
    psum_kernel<<<NB, 1024, 0, stream>>>(deg, bsum, NN);
    scan_bsum_kernel<<<1, 128, 0, stream>>>(bsum, NB);
    emit_kernel<<<NB, 1024, 0, stream>>>(deg, bsum, row_ptr, NN);
    copy_kernel<<<128, 256, 0, stream>>>(row_ptr, deg, NN);   // deg -> cursor
    fill_kernel<<<2048, 256, 0, stream>>>(ei, deg, ssrc, NE);

    // Conversions
    cvt_x_kernel<<<12500, 256, 0, stream>>>(x, xb, (long long)NN * DD / 4);
    cvt_w_kernel<<<(3 * 128 * 256 + 128 * 128 + 255) / 256, 256, 0, stream>>>(
        Wl, Wr, W1f, Wcat, Wp1);

    const int n_strips = NN / 32;   // 3125
    const int gather_grid = (NN * 64 + 255) / 256;

    const u16* hcur = xb;
    u16* hnext;
    for (int i = 0; i < 3; ++i) {
        hnext = (i == 0) ? bufA : ((hcur == bufA) ? bufB : bufA);
        gather_kernel<<<gather_grid, 256, 0, stream>>>(hcur, row_ptr, ssrc, P, NN);
        mfma_layer<8, true><<<n_strips, 256, 0, stream>>>(
            hcur, P, Wcat + (size_t)i * 128 * 256,
            bl + (size_t)i * DD, br + (size_t)i * DD, hnext, n_strips);
        hcur = hnext;
    }
    u16* p1out = (hcur == bufA) ? bufB : bufA;
    mfma_layer<4, false><<<n_strips, 256, 0, stream>>>(
        hcur, nullptr, Wp1, b1, nullptr, p1out, n_strips);
    post2_kernel<<<1024, 256, 0, stream>>>(p1out, W2, b2, outp, NN);
}